// Round 2
// baseline (181.737 us; speedup 1.0000x reference)
//
#include <hip/hip_runtime.h>
#include <math.h>

#define B_   64
#define L_   500
#define F_   256
#define H_   4
#define DK   64

typedef unsigned short u16;
typedef unsigned int   u32;
typedef __attribute__((ext_vector_type(8))) short short8;
typedef __attribute__((ext_vector_type(4))) float f32x4;

static __device__ __forceinline__ u16 f2bf(float f) {
    u32 u = __float_as_uint(f);
    u32 r = (u + 0x7FFFu + ((u >> 16) & 1u)) >> 16;
    return (u16)r;
}

// ---------------------------------------------------------------------------
// Prep: bf16 transposed weights + padded b2 + pad-zeroing of ws regions.
//  wqT/wvT/fcwT [256][256] ([n][k]); w1T[64][64]; w2T[512][64] (n>=500 -> 0)
//  b2p[512] float (tail -1e30); zero qh_bf pad rows + vhT cols 500..511.
// ---------------------------------------------------------------------------
__global__ __launch_bounds__(256) void prep_kernel(
    const float* __restrict__ wq, const float* __restrict__ wv,
    const float* __restrict__ fcw, const float* __restrict__ w1,
    const float* __restrict__ w2, const float* __restrict__ b2,
    u16* __restrict__ wqT, u16* __restrict__ wvT, u16* __restrict__ fcwT,
    u16* __restrict__ w1T, u16* __restrict__ w2T,
    u16* __restrict__ qh_bf, u16* __restrict__ vhT, float* __restrict__ b2p)
{
    int t = blockIdx.x * 256 + threadIdx.x;
    int stride = gridDim.x * 256;                 // 16384
    for (int i = t; i < 256 * 256; i += stride) {
        int n = i >> 8, k = i & 255;
        wqT[i]  = f2bf(wq[k * 256 + n]);
        wvT[i]  = f2bf(wv[k * 256 + n]);
        fcwT[i] = f2bf(fcw[k * 256 + n]);
    }
    for (int i = t; i < 64 * 64; i += stride) {
        int n = i >> 6, k = i & 63;
        w1T[i] = f2bf(w1[k * 64 + n]);
    }
    for (int i = t; i < 512 * 64; i += stride) {
        int n = i >> 6, k = i & 63;
        w2T[i] = f2bf(n < 500 ? w2[k * 500 + n] : 0.f);
    }
    // padded bias (tail -> exp() == 0)
    for (int i = t; i < 512; i += stride)
        b2p[i] = (i < 500) ? b2[i] : -1e30f;
    // zero qh_bf pad rows actually read by attn (rows 128000..128047);
    // [8195072, 8196096) holds b2p -> only zero below it.
    for (int i = t; i < 3072; i += stride)
        qh_bf[8192000 + i] = 0;
    // zero vhT pad cols 500..511 (16384 rows x 12 cols)
    for (int i = t; i < 196608; i += stride) {
        int r = i & 16383, c = i >> 14;
        vhT[(size_t)r * 512 + 500 + c] = 0;
    }
}

// ---------------------------------------------------------------------------
// Kernel 1: head projections, bf16 MFMA.
// grid (500, 2), block 512 = 8 waves in 2x4; block tile 64 rows x 256 cols.
// wave tile 32 x 64.  which=0: qh_bf [bh][500][64]; which=1: vhT [bh][64][512]
// ---------------------------------------------------------------------------
__global__ __launch_bounds__(512) void proj_kernel(
    const float* __restrict__ q, const float* __restrict__ v,
    const u16* __restrict__ wqT, const u16* __restrict__ wvT,
    u16* __restrict__ qh_bf, u16* __restrict__ vhT)
{
    const int which = blockIdx.y;
    const float* __restrict__ x = which ? v : q;
    const u16*   __restrict__ wT = which ? wvT : wqT;

    __shared__ u16 Xs[64][72];    // [m][k], pad 144 B
    __shared__ u16 Ws[256][72];   // [n][k], pad 144 B

    const int tid  = threadIdx.x;
    const int wvid = tid >> 6, ln = tid & 63;
    const int n16  = ln & 15, quad = ln >> 4;
    const int wr   = wvid >> 2, wc = wvid & 3;   // 2 x 4
    const int row0 = blockIdx.x * 64;

    f32x4 acc[2][4];
    #pragma unroll
    for (int mt = 0; mt < 2; mt++)
        #pragma unroll
        for (int nt = 0; nt < 4; nt++) acc[mt][nt] = (f32x4){0.f, 0.f, 0.f, 0.f};

    for (int kc = 0; kc < 256; kc += 64) {
        // stage X (fp32 -> bf16): 64 x 64
        #pragma unroll
        for (int j = 0; j < 2; j++) {
            int idx = tid + 512 * j;
            int m = idx >> 4, k4 = idx & 15;
            float4 a = *(const float4*)&x[(size_t)(row0 + m) * 256 + kc + k4 * 4];
            __align__(8) u16 t4[4] = {f2bf(a.x), f2bf(a.y), f2bf(a.z), f2bf(a.w)};
            *(uint2*)&Xs[m][k4 * 4] = *(const uint2*)t4;
        }
        // stage W^T: 256 x 64 bf16
        #pragma unroll
        for (int j = 0; j < 4; j++) {
            int idx = tid + 512 * j;
            int n = idx >> 3, k8 = idx & 7;
            *(uint4*)&Ws[n][k8 * 8] = *(const uint4*)&wT[n * 256 + kc + k8 * 8];
        }
        __syncthreads();
        #pragma unroll
        for (int ks = 0; ks < 2; ks++) {
            short8 af[2], bfr[4];
            #pragma unroll
            for (int mt = 0; mt < 2; mt++)
                af[mt] = *(const short8*)&Xs[wr * 32 + mt * 16 + n16][ks * 32 + quad * 8];
            #pragma unroll
            for (int nt = 0; nt < 4; nt++)
                bfr[nt] = *(const short8*)&Ws[wc * 64 + nt * 16 + n16][ks * 32 + quad * 8];
            #pragma unroll
            for (int mt = 0; mt < 2; mt++)
                #pragma unroll
                for (int nt = 0; nt < 4; nt++)
                    acc[mt][nt] = __builtin_amdgcn_mfma_f32_16x16x32_bf16(
                        af[mt], bfr[nt], acc[mt][nt], 0, 0, 0);
        }
        __syncthreads();
    }

    // h = wc (64-col groups), d = nt*16 + n16
    if (which == 0) {
        #pragma unroll
        for (int mt = 0; mt < 2; mt++) {
            int m0 = row0 + wr * 32 + mt * 16 + quad * 4;   // mult of 4
            int b  = m0 / 500;
            int l0 = m0 - 500 * b;                           // group never straddles b
            #pragma unroll
            for (int nt = 0; nt < 4; nt++) {
                int d = nt * 16 + n16;
                u16* dst = qh_bf + ((size_t)((b * 4 + wc) * 500 + l0)) * 64 + d;
                #pragma unroll
                for (int i = 0; i < 4; i++)
                    dst[(size_t)i * 64] = f2bf(acc[mt][nt][i]);
            }
        }
    } else {
        #pragma unroll
        for (int mt = 0; mt < 2; mt++) {
            int m0 = row0 + wr * 32 + mt * 16 + quad * 4;
            int b  = m0 / 500;
            int l0 = m0 - 500 * b;
            #pragma unroll
            for (int nt = 0; nt < 4; nt++) {
                int d = nt * 16 + n16;
                __align__(8) u16 t4[4];
                #pragma unroll
                for (int i = 0; i < 4; i++) t4[i] = f2bf(acc[mt][nt][i]);
                *(uint2*)&vhT[((size_t)((b * 4 + wc) * 64 + d)) * 512 + l0] =
                    *(const uint2*)t4;
            }
        }
    }
}

// ---------------------------------------------------------------------------
// Kernel 2: dense-synthesizer attention, bf16 MFMA — barrier-free flash-style.
// grid (256 bh, 8 row-chunks), block 256 = 4 waves, 16 rows/wave.
// Per-wave LDS scratch only (s and P); w2/v fragments read directly from
// global (L2-resident: w2T shared by all blocks, vhT chunk shared by the 8
// same-bh blocks on one XCD).  No max-pass softmax (logits bounded ~N(0,0.5),
// exp exact in f32; bf16 quantization of P is scale-invariant); biases folded
// into MFMA C-init.  All bf16 conversions via software-RNE f2bf.
// ---------------------------------------------------------------------------
__global__ __launch_bounds__(256, 4) void attn_kernel(
    const u16* __restrict__ qh, const u16* __restrict__ vhT,
    const u16* __restrict__ w1T, const float* __restrict__ b1,
    const u16* __restrict__ w2T, const float* __restrict__ b2p,
    u16* __restrict__ ctx)
{
    __shared__ u16 s_lds[4][16][72];    // per-wave: s = relu(qh@w1+b1), [row][k]
    __shared__ u16 p_lds[4][16][136];   // per-wave: current P chunk, [row][k]

    const int tid  = threadIdx.x;
    const int wv   = tid >> 6;
    const int ln   = tid & 63;
    const int n16  = ln & 15;
    const int quad = ln >> 4;
    const int bh   = blockIdx.x;
    const int r0   = blockIdx.y * 64 + wv * 16;

    // ---- Phase A: s = relu(qh @ w1 + b1)  (wave-private, no barrier) ----
    {
        const u16* qbase = qh + ((size_t)(bh * 500 + r0 + n16)) * 64;
        short8 a0 = *(const short8*)(qbase + quad * 8);
        short8 a1 = *(const short8*)(qbase + 32 + quad * 8);
        #pragma unroll
        for (int nt = 0; nt < 4; nt++) {
            const u16* wb = w1T + (nt * 16 + n16) * 64;
            short8 bb0 = *(const short8*)(wb + quad * 8);
            short8 bb1 = *(const short8*)(wb + 32 + quad * 8);
            float bias = b1[nt * 16 + n16];
            f32x4 c = {bias, bias, bias, bias};
            c = __builtin_amdgcn_mfma_f32_16x16x32_bf16(a0, bb0, c, 0, 0, 0);
            c = __builtin_amdgcn_mfma_f32_16x16x32_bf16(a1, bb1, c, 0, 0, 0);
            int col = nt * 16 + n16;
            #pragma unroll
            for (int i = 0; i < 4; i++)
                s_lds[wv][quad * 4 + i][col] = f2bf(fmaxf(c[i], 0.f));
        }
    }
    short8 sa0 = *(const short8*)&s_lds[wv][n16][quad * 8];
    short8 sa1 = *(const short8*)&s_lds[wv][n16][32 + quad * 8];

    f32x4 oacc[4];
    #pragma unroll
    for (int nt = 0; nt < 4; nt++) oacc[nt] = (f32x4){0.f, 0.f, 0.f, 0.f};
    float sm[4] = {0.f, 0.f, 0.f, 0.f};

    const u16* vbase = vhT + (size_t)(bh * 64) * 512;

    // ---- fused logits -> exp -> PV over 4 col-chunks of 128 ----
    #pragma unroll 1
    for (int cc = 0; cc < 4; cc++) {
        // logits chunk: cols cc*128 .. +127 (w2 frags direct from L2)
        f32x4 c8[8];
        #pragma unroll
        for (int t = 0; t < 8; t++) {
            const u16* wb = w2T + (size_t)(cc * 128 + t * 16 + n16) * 64;
            short8 b0  = *(const short8*)(wb + quad * 8);
            short8 b1v = *(const short8*)(wb + 32 + quad * 8);
            float bias = b2p[cc * 128 + t * 16 + n16];
            f32x4 c = {bias, bias, bias, bias};
            c = __builtin_amdgcn_mfma_f32_16x16x32_bf16(sa0, b0, c, 0, 0, 0);
            c = __builtin_amdgcn_mfma_f32_16x16x32_bf16(sa1, b1v, c, 0, 0, 0);
            c8[t] = c;
        }
        // exp (no max subtraction) + running sum + P -> bf16 -> wave-local LDS
        #pragma unroll
        for (int t = 0; t < 8; t++) {
            int col = t * 16 + n16;
            #pragma unroll
            for (int i = 0; i < 4; i++) {
                float e = __expf(c8[t][i]);
                sm[i] += e;
                p_lds[wv][quad * 4 + i][col] = f2bf(e);
            }
        }
        // PV: v frags direct from L2 (same-wave LDS ordering covers P RAW)
        #pragma unroll
        for (int ks = 0; ks < 4; ks++) {
            short8 pa = *(const short8*)&p_lds[wv][n16][ks * 32 + quad * 8];
            #pragma unroll
            for (int nt = 0; nt < 4; nt++) {
                short8 vb = *(const short8*)(vbase +
                    (size_t)(nt * 16 + n16) * 512 + cc * 128 + ks * 32 + quad * 8);
                oacc[nt] = __builtin_amdgcn_mfma_f32_16x16x32_bf16(pa, vb, oacc[nt], 0, 0, 0);
            }
        }
    }

    // ---- row-sum reduce over the 16 col-lanes, then scaled bf16 store ----
    #pragma unroll
    for (int off = 1; off < 16; off <<= 1) {
        #pragma unroll
        for (int i = 0; i < 4; i++) sm[i] += __shfl_xor(sm[i], off);
    }

    const int b = bh >> 2, h = bh & 3;
    #pragma unroll
    for (int i = 0; i < 4; i++) {
        int lrow = r0 + quad * 4 + i;
        if (lrow < 500) {
            float s = 1.f / sm[i];
            u16* dst = &ctx[((size_t)(b * 500 + lrow)) * 256 + h * 64];
            #pragma unroll
            for (int nt = 0; nt < 4; nt++)
                dst[nt * 16 + n16] = f2bf(oacc[nt][i] * s);
        }
    }
}

// ---------------------------------------------------------------------------
// Kernel 3: out = LayerNorm(ctx @ fc_w + q), bf16 MFMA + fused LN epilogue.
// grid (500), block 512 = 8 waves in 2x4; block tile 64 rows x 256 cols.
// ---------------------------------------------------------------------------
__global__ __launch_bounds__(512) void final_kernel(
    const u16* __restrict__ ctx, const u16* __restrict__ fcwT,
    const float* __restrict__ qres, const float* __restrict__ g,
    const float* __restrict__ bta, float* __restrict__ out)
{
    __shared__ u16 Xs[64][72];
    __shared__ u16 Ws[256][72];
    __shared__ float red[4][2][64];   // [wc][s1|s2][row]
    __shared__ float murs[2][64];     // [mu|rs][row]

    const int tid  = threadIdx.x;
    const int wvid = tid >> 6, ln = tid & 63;
    const int n16  = ln & 15, quad = ln >> 4;
    const int wr   = wvid >> 2, wc = wvid & 3;   // 2 x 4
    const int row0 = blockIdx.x * 64;

    f32x4 acc[2][4];
    #pragma unroll
    for (int mt = 0; mt < 2; mt++)
        #pragma unroll
        for (int nt = 0; nt < 4; nt++) acc[mt][nt] = (f32x4){0.f, 0.f, 0.f, 0.f};

    for (int kc = 0; kc < 256; kc += 64) {
        // stage X: 64 x 64 bf16
        {
            int idx = tid;
            int m = idx >> 3, k8 = idx & 7;
            *(uint4*)&Xs[m][k8 * 8] =
                *(const uint4*)&ctx[(size_t)(row0 + m) * 256 + kc + k8 * 8];
        }
        // stage W^T: 256 x 64 bf16
        #pragma unroll
        for (int j = 0; j < 4; j++) {
            int idx = tid + 512 * j;
            int n = idx >> 3, k8 = idx & 7;
            *(uint4*)&Ws[n][k8 * 8] = *(const uint4*)&fcwT[n * 256 + kc + k8 * 8];
        }
        __syncthreads();
        #pragma unroll
        for (int ks = 0; ks < 2; ks++) {
            short8 af[2], bfr[4];
            #pragma unroll
            for (int mt = 0; mt < 2; mt++)
                af[mt] = *(const short8*)&Xs[wr * 32 + mt * 16 + n16][ks * 32 + quad * 8];
            #pragma unroll
            for (int nt = 0; nt < 4; nt++)
                bfr[nt] = *(const short8*)&Ws[wc * 64 + nt * 16 + n16][ks * 32 + quad * 8];
            #pragma unroll
            for (int mt = 0; mt < 2; mt++)
                #pragma unroll
                for (int nt = 0; nt < 4; nt++)
                    acc[mt][nt] = __builtin_amdgcn_mfma_f32_16x16x32_bf16(
                        af[mt], bfr[nt], acc[mt][nt], 0, 0, 0);
        }
        __syncthreads();
    }

    // residual add
    #pragma unroll
    for (int mt = 0; mt < 2; mt++) {
        int m0 = row0 + wr * 32 + mt * 16 + quad * 4;
        #pragma unroll
        for (int i = 0; i < 4; i++) {
            const float* rp = &qres[(size_t)(m0 + i) * 256 + wc * 64 + n16];
            #pragma unroll
            for (int nt = 0; nt < 4; nt++)
                acc[mt][nt][i] += rp[nt * 16];
        }
    }
    // per-row partial sums -> LDS
    #pragma unroll
    for (int mt = 0; mt < 2; mt++) {
        #pragma unroll
        for (int i = 0; i < 4; i++) {
            float s1 = 0.f, s2 = 0.f;
            #pragma unroll
            for (int nt = 0; nt < 4; nt++) {
                float vv = acc[mt][nt][i];
                s1 += vv; s2 += vv * vv;
            }
            #pragma unroll
            for (int off = 1; off < 16; off <<= 1) {
                s1 += __shfl_xor(s1, off);
                s2 += __shfl_xor(s2, off);
            }
            if (n16 == 0) {
                int r = wr * 32 + mt * 16 + quad * 4 + i;
                red[wc][0][r] = s1;
                red[wc][1][r] = s2;
            }
        }
    }
    __syncthreads();
    if (tid < 64) {
        float S1 = red[0][0][tid] + red[1][0][tid] + red[2][0][tid] + red[3][0][tid];
        float S2 = red[0][1][tid] + red[1][1][tid] + red[2][1][tid] + red[3][1][tid];
        float mu  = S1 * 0.00390625f;
        float var = S2 * 0.00390625f - mu * mu;
        murs[0][tid] = mu;
        murs[1][tid] = rsqrtf(var + 1e-6f);
    }
    __syncthreads();

    float gv[4], bv[4];
    #pragma unroll
    for (int nt = 0; nt < 4; nt++) {
        int col = wc * 64 + nt * 16 + n16;
        gv[nt] = g[col];
        bv[nt] = bta[col];
    }
    #pragma unroll
    for (int mt = 0; mt < 2; mt++) {
        int rb = wr * 32 + mt * 16 + quad * 4;
        #pragma unroll
        for (int i = 0; i < 4; i++) {
            float mu = murs[0][rb + i];
            float rs = murs[1][rb + i];
            float* op = &out[(size_t)(row0 + rb + i) * 256 + wc * 64 + n16];
            #pragma unroll
            for (int nt = 0; nt < 4; nt++)
                op[nt * 16] = (acc[mt][nt][i] - mu) * rs * gv[nt] + bv[nt];
        }
    }
}

// ---------------------------------------------------------------------------
extern "C" void kernel_launch(void* const* d_in, const int* in_sizes, int n_in,
                              void* d_out, int out_size, void* d_ws, size_t ws_size,
                              hipStream_t stream)
{
    const float* q   = (const float*)d_in[0];
    const float* v   = (const float*)d_in[2];
    const float* wqs = (const float*)d_in[3];
    const float* wvs = (const float*)d_in[4];
    const float* w1  = (const float*)d_in[5];
    const float* b1  = (const float*)d_in[6];
    const float* w2  = (const float*)d_in[7];
    const float* b2  = (const float*)d_in[8];
    const float* fcw = (const float*)d_in[9];
    const float* lng = (const float*)d_in[10];
    const float* lnb = (const float*)d_in[11];
    float* out = (float*)d_out;

    u16* qh_bf = (u16*)d_ws;            // 8,200,192 (rows >=500*256 are pad)
    u16* vhT   = qh_bf + 8200192;       // 8,388,608
    u16* w1T   = vhT + 8388608;         // 4,096
    u16* w2T   = w1T + 4096;            // 32,768
    u16* wqT   = w2T + 32768;           // 65,536
    u16* wvT   = wqT + 65536;           // 65,536
    u16* fcwT  = wvT + 65536;           // 65,536
    u16* ctx   = fcwT + 65536;          // 8,192,000
    float* b2p = (float*)(qh_bf + 8195072);  // 512 floats inside qh_bf tail pad

    prep_kernel <<<dim3(64),     256, 0, stream>>>(wqs, wvs, fcw, w1, w2, b2,
                                                   wqT, wvT, fcwT, w1T, w2T,
                                                   qh_bf, vhT, b2p);
    proj_kernel <<<dim3(500, 2), 512, 0, stream>>>(q, v, wqT, wvT, qh_bf, vhT);
    attn_kernel <<<dim3(256, 8), 256, 0, stream>>>(qh_bf, vhT, w1T, b1, w2T, b2p, ctx);
    final_kernel<<<dim3(500),    512, 0, stream>>>(ctx, fcwT, q, lng, lnb, out);
}

// Round 3
// 98.455 us; speedup vs baseline: 1.8459x; 1.8459x over previous
//
#include <hip/hip_runtime.h>
#include <math.h>

#define B_   64
#define L_   500
#define F_   256
#define H_   4
#define DK   64

typedef unsigned short u16;
typedef unsigned int   u32;
typedef __attribute__((ext_vector_type(8))) short short8;
typedef __attribute__((ext_vector_type(4))) float f32x4;

static __device__ __forceinline__ u16 f2bf(float f) {
    u32 u = __float_as_uint(f);
    u32 r = (u + 0x7FFFu + ((u >> 16) & 1u)) >> 16;
    return (u16)r;
}

typedef __attribute__((address_space(3))) u32 lds32;
typedef const __attribute__((address_space(1))) u32 gbl32;
// async global->LDS DMA, 16 B/lane, LDS dest = uniform base + lane*16
static __device__ __forceinline__ void gload_lds16(const u16* g, u16* l) {
    __builtin_amdgcn_global_load_lds((gbl32*)g, (lds32*)l, 16, 0, 0);
}

// ---------------------------------------------------------------------------
// Prep: bf16 transposed weights + padded b2 + pad-zeroing of ws regions.
//  wqT/wvT/fcwT [256][256] ([n][k]); w1T[64][64]
//  w2sw: chunk-tiled + XOR-swizzled: [cc=8][row=64][k=64],
//        w2sw[cc][row][k] = w2[k ^ ((row&7)<<3)][cc*64+row]  (col>=500 -> 0)
//  b2p[512] float (tail -1e30); zero qh_bf pad rows + vhT swizzled pad slots.
// ---------------------------------------------------------------------------
__global__ __launch_bounds__(256) void prep_kernel(
    const float* __restrict__ wq, const float* __restrict__ wv,
    const float* __restrict__ fcw, const float* __restrict__ w1,
    const float* __restrict__ w2, const float* __restrict__ b2,
    u16* __restrict__ wqT, u16* __restrict__ wvT, u16* __restrict__ fcwT,
    u16* __restrict__ w1T, u16* __restrict__ w2sw,
    u16* __restrict__ qh_bf, u16* __restrict__ vhT, float* __restrict__ b2p)
{
    int t = blockIdx.x * 256 + threadIdx.x;
    int stride = gridDim.x * 256;                 // 16384
    for (int i = t; i < 256 * 256; i += stride) {
        int n = i >> 8, k = i & 255;
        wqT[i]  = f2bf(wq[k * 256 + n]);
        wvT[i]  = f2bf(wv[k * 256 + n]);
        fcwT[i] = f2bf(fcw[k * 256 + n]);
    }
    for (int i = t; i < 64 * 64; i += stride) {
        int n = i >> 6, k = i & 63;
        w1T[i] = f2bf(w1[k * 64 + n]);
    }
    // w2 chunk-tiled + swizzled
    for (int i = t; i < 512 * 64; i += stride) {
        int cc  = i >> 12;            // chunk of 64 cols
        int row = (i >> 6) & 63;      // col within chunk
        int kc  = i & 63;
        int n   = cc * 64 + row;      // global output col
        int kl  = kc ^ ((row & 7) << 3);
        w2sw[i] = f2bf(n < 500 ? w2[kl * 500 + n] : 0.f);
    }
    // padded bias (tail -> exp() == 0)
    for (int i = t; i < 512; i += stride)
        b2p[i] = (i < 500) ? b2[i] : -1e30f;
    // zero qh_bf pad rows read by attn (rows >= 128000); b2p lives at 8195072+
    for (int i = t; i < 3072; i += stride)
        qh_bf[8192000 + i] = 0;
    // zero vhT swizzled pad slots: chunk 7, k 52..63 for every (bh, d)
    for (int i = t; i < 196608; i += stride) {
        int bh = i / 768;
        int r  = i - bh * 768;
        int d  = r / 12;
        int kk = 52 + (r - d * 12);
        vhT[((size_t)((bh * 8 + 7) * 64 + d)) * 64 + (kk ^ ((d & 7) << 3))] = 0;
    }
}

// ---------------------------------------------------------------------------
// Kernel 1: head projections, bf16 MFMA.
// grid (500, 2), block 512 = 8 waves in 2x4; block tile 64 rows x 256 cols.
// which=0: qh_bf [bh][500][64]
// which=1: vhT chunk-tiled+swizzled [bh][cc=8][d=64][k=64],
//          vhT[bh][cc][d][k ^ ((d&7)<<3)] = v_head[bh][d][cc*64+k]
// ---------------------------------------------------------------------------
__global__ __launch_bounds__(512) void proj_kernel(
    const float* __restrict__ q, const float* __restrict__ v,
    const u16* __restrict__ wqT, const u16* __restrict__ wvT,
    u16* __restrict__ qh_bf, u16* __restrict__ vhT)
{
    const int which = blockIdx.y;
    const float* __restrict__ x = which ? v : q;
    const u16*   __restrict__ wT = which ? wvT : wqT;

    __shared__ u16 Xs[64][72];    // [m][k], pad 144 B
    __shared__ u16 Ws[256][72];   // [n][k], pad 144 B

    const int tid  = threadIdx.x;
    const int wvid = tid >> 6, ln = tid & 63;
    const int n16  = ln & 15, quad = ln >> 4;
    const int wr   = wvid >> 2, wc = wvid & 3;   // 2 x 4
    const int row0 = blockIdx.x * 64;

    f32x4 acc[2][4];
    #pragma unroll
    for (int mt = 0; mt < 2; mt++)
        #pragma unroll
        for (int nt = 0; nt < 4; nt++) acc[mt][nt] = (f32x4){0.f, 0.f, 0.f, 0.f};

    for (int kc = 0; kc < 256; kc += 64) {
        // stage X (fp32 -> bf16): 64 x 64
        #pragma unroll
        for (int j = 0; j < 2; j++) {
            int idx = tid + 512 * j;
            int m = idx >> 4, k4 = idx & 15;
            float4 a = *(const float4*)&x[(size_t)(row0 + m) * 256 + kc + k4 * 4];
            __align__(8) u16 t4[4] = {f2bf(a.x), f2bf(a.y), f2bf(a.z), f2bf(a.w)};
            *(uint2*)&Xs[m][k4 * 4] = *(const uint2*)t4;
        }
        // stage W^T: 256 x 64 bf16
        #pragma unroll
        for (int j = 0; j < 4; j++) {
            int idx = tid + 512 * j;
            int n = idx >> 3, k8 = idx & 7;
            *(uint4*)&Ws[n][k8 * 8] = *(const uint4*)&wT[n * 256 + kc + k8 * 8];
        }
        __syncthreads();
        #pragma unroll
        for (int ks = 0; ks < 2; ks++) {
            short8 af[2], bfr[4];
            #pragma unroll
            for (int mt = 0; mt < 2; mt++)
                af[mt] = *(const short8*)&Xs[wr * 32 + mt * 16 + n16][ks * 32 + quad * 8];
            #pragma unroll
            for (int nt = 0; nt < 4; nt++)
                bfr[nt] = *(const short8*)&Ws[wc * 64 + nt * 16 + n16][ks * 32 + quad * 8];
            #pragma unroll
            for (int mt = 0; mt < 2; mt++)
                #pragma unroll
                for (int nt = 0; nt < 4; nt++)
                    acc[mt][nt] = __builtin_amdgcn_mfma_f32_16x16x32_bf16(
                        af[mt], bfr[nt], acc[mt][nt], 0, 0, 0);
        }
        __syncthreads();
    }

    // h = wc (64-col groups), d = nt*16 + n16
    if (which == 0) {
        #pragma unroll
        for (int mt = 0; mt < 2; mt++) {
            int m0 = row0 + wr * 32 + mt * 16 + quad * 4;   // mult of 4
            int b  = m0 / 500;
            int l0 = m0 - 500 * b;                           // group never straddles b
            #pragma unroll
            for (int nt = 0; nt < 4; nt++) {
                int d = nt * 16 + n16;
                u16* dst = qh_bf + ((size_t)((b * 4 + wc) * 500 + l0)) * 64 + d;
                #pragma unroll
                for (int i = 0; i < 4; i++)
                    dst[(size_t)i * 64] = f2bf(acc[mt][nt][i]);
            }
        }
    } else {
        #pragma unroll
        for (int mt = 0; mt < 2; mt++) {
            int m0 = row0 + wr * 32 + mt * 16 + quad * 4;
            int b  = m0 / 500;
            int l0 = m0 - 500 * b;                           // 4-aligned
            int cc = l0 >> 6, kk = l0 & 63;
            #pragma unroll
            for (int nt = 0; nt < 4; nt++) {
                int d = nt * 16 + n16;
                __align__(8) u16 t4[4];
                #pragma unroll
                for (int i = 0; i < 4; i++) t4[i] = f2bf(acc[mt][nt][i]);
                size_t base = ((size_t)(((b * 4 + wc) * 8 + cc) * 64 + d)) * 64;
                *(uint2*)&vhT[base + (kk ^ ((d & 7) << 3))] = *(const uint2*)t4;
            }
        }
    }
}

// ---------------------------------------------------------------------------
// Kernel 2: dense-synthesizer attention — chunked, async-LDS-staged (T3).
// grid (256 bh, 8 row-chunks), block 256 = 4 waves, 16 rows/wave.
// Per 64-col chunk: stage next chunk's w2 (8KB) + v (8KB) via global_load_lds
// (double-buffered, pre-swizzled global layouts -> conflict-free XOR reads),
// then logits MFMA -> exp -> PV MFMA on the current buffers.  One barrier
// (= vmcnt drain) per chunk.  Per-wave s/P scratch aliased (same-wave order).
// LDS 41 KB -> 3 blocks/CU; VGPR ~100 -> occupancy no longer register-bound.
// ---------------------------------------------------------------------------
__global__ __launch_bounds__(256, 3) void attn_kernel(
    const u16* __restrict__ qh, const u16* __restrict__ vhT,
    const u16* __restrict__ w1T, const float* __restrict__ b1,
    const u16* __restrict__ w2sw, const float* __restrict__ b2p,
    u16* __restrict__ ctx)
{
    __shared__ __align__(16) u16 w2s[2][4096];    // [buf][row*64 + k^swz]
    __shared__ __align__(16) u16 v_s[2][4096];    // [buf][d*64 + k^swz]
    __shared__ __align__(16) u16 scr[4][16][72];  // per-wave s / P scratch

    const int tid  = threadIdx.x;
    const int wv   = tid >> 6;
    const int ln   = tid & 63;
    const int n16  = ln & 15;
    const int quad = ln >> 4;
    const int bh   = blockIdx.x;
    const int r0   = blockIdx.y * 64 + wv * 16;

    const u16* vg = vhT + (size_t)bh * 32768;     // 8 chunks x 4096

    // issue chunk-0 staging first; latency hides under Phase A
    {
        int off = wv * 1024 + ln * 8;
        gload_lds16(w2sw + off,        &w2s[0][wv * 1024]);
        gload_lds16(w2sw + off + 512,  &w2s[0][wv * 1024 + 512]);
        gload_lds16(vg + off,          &v_s[0][wv * 1024]);
        gload_lds16(vg + off + 512,    &v_s[0][wv * 1024 + 512]);
    }

    // ---- Phase A: s = relu(qh @ w1 + b1)  (wave-private) ----
    {
        const u16* qbase = qh + ((size_t)(bh * 500 + r0 + n16)) * 64;
        short8 a0 = *(const short8*)(qbase + quad * 8);
        short8 a1 = *(const short8*)(qbase + 32 + quad * 8);
        #pragma unroll
        for (int nt = 0; nt < 4; nt++) {
            const u16* wb = w1T + (nt * 16 + n16) * 64;
            short8 bb0 = *(const short8*)(wb + quad * 8);
            short8 bb1 = *(const short8*)(wb + 32 + quad * 8);
            float bias = b1[nt * 16 + n16];
            f32x4 c = {bias, bias, bias, bias};
            c = __builtin_amdgcn_mfma_f32_16x16x32_bf16(a0, bb0, c, 0, 0, 0);
            c = __builtin_amdgcn_mfma_f32_16x16x32_bf16(a1, bb1, c, 0, 0, 0);
            int col = nt * 16 + n16;
            #pragma unroll
            for (int i = 0; i < 4; i++)
                scr[wv][quad * 4 + i][col] = f2bf(fmaxf(c[i], 0.f));
        }
    }
    short8 sa0 = *(const short8*)&scr[wv][n16][quad * 8];
    short8 sa1 = *(const short8*)&scr[wv][n16][32 + quad * 8];

    f32x4 oacc[4];
    #pragma unroll
    for (int nt = 0; nt < 4; nt++) oacc[nt] = (f32x4){0.f, 0.f, 0.f, 0.f};
    float sm[4] = {0.f, 0.f, 0.f, 0.f};

    __syncthreads();   // chunk-0 staging complete; scr s-values consumed to regs

    #pragma unroll 2
    for (int cc = 0; cc < 8; cc++) {
        const int cur = cc & 1;
        if (cc < 7) {   // stage next chunk into the other buffer
            int off = wv * 1024 + ln * 8;
            const u16* gw = w2sw + (cc + 1) * 4096 + off;
            const u16* gv = vg + (size_t)(cc + 1) * 4096 + off;
            gload_lds16(gw,        &w2s[cur ^ 1][wv * 1024]);
            gload_lds16(gw + 512,  &w2s[cur ^ 1][wv * 1024 + 512]);
            gload_lds16(gv,        &v_s[cur ^ 1][wv * 1024]);
            gload_lds16(gv + 512,  &v_s[cur ^ 1][wv * 1024 + 512]);
        }
        const u16* wb   = &w2s[cur][0];
        const u16* vbuf = &v_s[cur][0];

        // logits: 4 col-tiles of 16
        f32x4 c8[4];
        #pragma unroll
        for (int t = 0; t < 4; t++) {
            int r  = t * 16 + n16;
            int sw = (r & 7) << 3;
            short8 b0  = *(const short8*)&wb[r * 64 + ((quad * 8) ^ sw)];
            short8 b1v = *(const short8*)&wb[r * 64 + ((32 + quad * 8) ^ sw)];
            float bias = b2p[cc * 64 + r];
            f32x4 c = {bias, bias, bias, bias};
            c = __builtin_amdgcn_mfma_f32_16x16x32_bf16(sa0, b0, c, 0, 0, 0);
            c = __builtin_amdgcn_mfma_f32_16x16x32_bf16(sa1, b1v, c, 0, 0, 0);
            c8[t] = c;
        }
        // exp (no max-pass) + running sum; P -> bf16 -> wave-local scratch
        #pragma unroll
        for (int t = 0; t < 4; t++) {
            int col = t * 16 + n16;
            #pragma unroll
            for (int i = 0; i < 4; i++) {
                float e = __expf(c8[t][i]);
                sm[i] += e;
                scr[wv][quad * 4 + i][col] = f2bf(e);
            }
        }
        // PV on this chunk
        #pragma unroll
        for (int ks = 0; ks < 2; ks++) {
            short8 pa = *(const short8*)&scr[wv][n16][ks * 32 + quad * 8];
            #pragma unroll
            for (int nt = 0; nt < 4; nt++) {
                int d   = nt * 16 + n16;
                int swd = (d & 7) << 3;
                short8 vb2 = *(const short8*)&vbuf[d * 64 + ((ks * 32 + quad * 8) ^ swd)];
                oacc[nt] = __builtin_amdgcn_mfma_f32_16x16x32_bf16(pa, vb2, oacc[nt], 0, 0, 0);
            }
        }
        __syncthreads();   // drains staging vmcnt + protects buffer reuse
    }

    // ---- row-sum reduce over the 16 col-lanes, then scaled bf16 store ----
    #pragma unroll
    for (int off = 1; off < 16; off <<= 1) {
        #pragma unroll
        for (int i = 0; i < 4; i++) sm[i] += __shfl_xor(sm[i], off);
    }

    const int b = bh >> 2, h = bh & 3;
    #pragma unroll
    for (int i = 0; i < 4; i++) {
        int lrow = r0 + quad * 4 + i;
        if (lrow < 500) {
            float s = 1.f / sm[i];
            u16* dst = &ctx[((size_t)(b * 500 + lrow)) * 256 + h * 64];
            #pragma unroll
            for (int nt = 0; nt < 4; nt++)
                dst[nt * 16 + n16] = f2bf(oacc[nt][i] * s);
        }
    }
}

// ---------------------------------------------------------------------------
// Kernel 3: out = LayerNorm(ctx @ fc_w + q), bf16 MFMA + fused LN epilogue.
// grid (500), block 512 = 8 waves in 2x4; block tile 64 rows x 256 cols.
// ---------------------------------------------------------------------------
__global__ __launch_bounds__(512) void final_kernel(
    const u16* __restrict__ ctx, const u16* __restrict__ fcwT,
    const float* __restrict__ qres, const float* __restrict__ g,
    const float* __restrict__ bta, float* __restrict__ out)
{
    __shared__ u16 Xs[64][72];
    __shared__ u16 Ws[256][72];
    __shared__ float red[4][2][64];   // [wc][s1|s2][row]
    __shared__ float murs[2][64];     // [mu|rs][row]

    const int tid  = threadIdx.x;
    const int wvid = tid >> 6, ln = tid & 63;
    const int n16  = ln & 15, quad = ln >> 4;
    const int wr   = wvid >> 2, wc = wvid & 3;   // 2 x 4
    const int row0 = blockIdx.x * 64;

    f32x4 acc[2][4];
    #pragma unroll
    for (int mt = 0; mt < 2; mt++)
        #pragma unroll
        for (int nt = 0; nt < 4; nt++) acc[mt][nt] = (f32x4){0.f, 0.f, 0.f, 0.f};

    for (int kc = 0; kc < 256; kc += 64) {
        // stage X: 64 x 64 bf16
        {
            int idx = tid;
            int m = idx >> 3, k8 = idx & 7;
            *(uint4*)&Xs[m][k8 * 8] =
                *(const uint4*)&ctx[(size_t)(row0 + m) * 256 + kc + k8 * 8];
        }
        // stage W^T: 256 x 64 bf16
        #pragma unroll
        for (int j = 0; j < 4; j++) {
            int idx = tid + 512 * j;
            int n = idx >> 3, k8 = idx & 7;
            *(uint4*)&Ws[n][k8 * 8] = *(const uint4*)&fcwT[n * 256 + kc + k8 * 8];
        }
        __syncthreads();
        #pragma unroll
        for (int ks = 0; ks < 2; ks++) {
            short8 af[2], bfr[4];
            #pragma unroll
            for (int mt = 0; mt < 2; mt++)
                af[mt] = *(const short8*)&Xs[wr * 32 + mt * 16 + n16][ks * 32 + quad * 8];
            #pragma unroll
            for (int nt = 0; nt < 4; nt++)
                bfr[nt] = *(const short8*)&Ws[wc * 64 + nt * 16 + n16][ks * 32 + quad * 8];
            #pragma unroll
            for (int mt = 0; mt < 2; mt++)
                #pragma unroll
                for (int nt = 0; nt < 4; nt++)
                    acc[mt][nt] = __builtin_amdgcn_mfma_f32_16x16x32_bf16(
                        af[mt], bfr[nt], acc[mt][nt], 0, 0, 0);
        }
        __syncthreads();
    }

    // residual add
    #pragma unroll
    for (int mt = 0; mt < 2; mt++) {
        int m0 = row0 + wr * 32 + mt * 16 + quad * 4;
        #pragma unroll
        for (int i = 0; i < 4; i++) {
            const float* rp = &qres[(size_t)(m0 + i) * 256 + wc * 64 + n16];
            #pragma unroll
            for (int nt = 0; nt < 4; nt++)
                acc[mt][nt][i] += rp[nt * 16];
        }
    }
    // per-row partial sums -> LDS
    #pragma unroll
    for (int mt = 0; mt < 2; mt++) {
        #pragma unroll
        for (int i = 0; i < 4; i++) {
            float s1 = 0.f, s2 = 0.f;
            #pragma unroll
            for (int nt = 0; nt < 4; nt++) {
                float vv = acc[mt][nt][i];
                s1 += vv; s2 += vv * vv;
            }
            #pragma unroll
            for (int off = 1; off < 16; off <<= 1) {
                s1 += __shfl_xor(s1, off);
                s2 += __shfl_xor(s2, off);
            }
            if (n16 == 0) {
                int r = wr * 32 + mt * 16 + quad * 4 + i;
                red[wc][0][r] = s1;
                red[wc][1][r] = s2;
            }
        }
    }
    __syncthreads();
    if (tid < 64) {
        float S1 = red[0][0][tid] + red[1][0][tid] + red[2][0][tid] + red[3][0][tid];
        float S2 = red[0][1][tid] + red[1][1][tid] + red[2][1][tid] + red[3][1][tid];
        float mu  = S1 * 0.00390625f;
        float var = S2 * 0.00390625f - mu * mu;
        murs[0][tid] = mu;
        murs[1][tid] = rsqrtf(var + 1e-6f);
    }
    __syncthreads();

    float gv[4], bv[4];
    #pragma unroll
    for (int nt = 0; nt < 4; nt++) {
        int col = wc * 64 + nt * 16 + n16;
        gv[nt] = g[col];
        bv[nt] = bta[col];
    }
    #pragma unroll
    for (int mt = 0; mt < 2; mt++) {
        int rb = wr * 32 + mt * 16 + quad * 4;
        #pragma unroll
        for (int i = 0; i < 4; i++) {
            float mu = murs[0][rb + i];
            float rs = murs[1][rb + i];
            float* op = &out[(size_t)(row0 + rb + i) * 256 + wc * 64 + n16];
            #pragma unroll
            for (int nt = 0; nt < 4; nt++)
                op[nt * 16] = (acc[mt][nt][i] - mu) * rs * gv[nt] + bv[nt];
        }
    }
}

// ---------------------------------------------------------------------------
extern "C" void kernel_launch(void* const* d_in, const int* in_sizes, int n_in,
                              void* d_out, int out_size, void* d_ws, size_t ws_size,
                              hipStream_t stream)
{
    const float* q   = (const float*)d_in[0];
    const float* v   = (const float*)d_in[2];
    const float* wqs = (const float*)d_in[3];
    const float* wvs = (const float*)d_in[4];
    const float* w1  = (const float*)d_in[5];
    const float* b1  = (const float*)d_in[6];
    const float* w2  = (const float*)d_in[7];
    const float* b2  = (const float*)d_in[8];
    const float* fcw = (const float*)d_in[9];
    const float* lng = (const float*)d_in[10];
    const float* lnb = (const float*)d_in[11];
    float* out = (float*)d_out;

    u16* qh_bf = (u16*)d_ws;            // 8,200,192 (rows >=500*256 are pad)
    u16* vhT   = qh_bf + 8200192;       // 8,388,608 (chunk-tiled + swizzled)
    u16* w1T   = vhT + 8388608;         // 4,096
    u16* w2sw  = w1T + 4096;            // 32,768 (chunk-tiled + swizzled)
    u16* wqT   = w2sw + 32768;          // 65,536
    u16* wvT   = wqT + 65536;           // 65,536
    u16* fcwT  = wvT + 65536;           // 65,536
    u16* ctx   = fcwT + 65536;          // 8,192,000
    float* b2p = (float*)(qh_bf + 8195072);  // 512 floats inside qh_bf tail pad

    prep_kernel <<<dim3(64),     256, 0, stream>>>(wqs, wvs, fcw, w1, w2, b2,
                                                   wqT, wvT, fcwT, w1T, w2sw,
                                                   qh_bf, vhT, b2p);
    proj_kernel <<<dim3(500, 2), 512, 0, stream>>>(q, v, wqT, wvT, qh_bf, vhT);
    attn_kernel <<<dim3(256, 8), 256, 0, stream>>>(qh_bf, vhT, w1T, b1, w2sw, b2p, ctx);
    final_kernel<<<dim3(500),    512, 0, stream>>>(ctx, fcwT, q, lng, lnb, out);
}

// Round 4
// 95.572 us; speedup vs baseline: 1.9016x; 1.0302x over previous
//
#include <hip/hip_runtime.h>
#include <math.h>

#define B_   64
#define L_   500
#define F_   256
#define H_   4
#define DK   64

typedef unsigned short u16;
typedef unsigned int   u32;
typedef __attribute__((ext_vector_type(8))) short short8;
typedef __attribute__((ext_vector_type(4))) float f32x4;

static __device__ __forceinline__ u16 f2bf(float f) {
    u32 u = __float_as_uint(f);
    u32 r = (u + 0x7FFFu + ((u >> 16) & 1u)) >> 16;
    return (u16)r;
}

typedef __attribute__((address_space(3))) u32 lds32;
typedef const __attribute__((address_space(1))) u32 gbl32;
// async global->LDS DMA, 16 B/lane, LDS dest = uniform base + lane*16
static __device__ __forceinline__ void gload_lds16(const u16* g, u16* l) {
    __builtin_amdgcn_global_load_lds((gbl32*)g, (lds32*)l, 16, 0, 0);
}

// ---------------------------------------------------------------------------
// Prep: bf16 transposed weights + padded b2 + pad-zeroing of ws regions.
//  wqT/wvT/fcwT [256][256] ([n][k]); w1T[64][64]
//  w2sw: chunk-tiled + XOR-swizzled: [cc=8][row=64][k=64],
//        w2sw[cc][row][k] = w2[k ^ ((row&7)<<3)][cc*64+row]  (col>=500 -> 0)
//  b2p[512] float (tail -1e30); zero qh_bf pad rows + vhT swizzled pad slots.
// ---------------------------------------------------------------------------
__global__ __launch_bounds__(256) void prep_kernel(
    const float* __restrict__ wq, const float* __restrict__ wv,
    const float* __restrict__ fcw, const float* __restrict__ w1,
    const float* __restrict__ w2, const float* __restrict__ b2,
    u16* __restrict__ wqT, u16* __restrict__ wvT, u16* __restrict__ fcwT,
    u16* __restrict__ w1T, u16* __restrict__ w2sw,
    u16* __restrict__ qh_bf, u16* __restrict__ vhT, float* __restrict__ b2p)
{
    int t = blockIdx.x * 256 + threadIdx.x;
    int stride = gridDim.x * 256;                 // 16384
    for (int i = t; i < 256 * 256; i += stride) {
        int n = i >> 8, k = i & 255;
        wqT[i]  = f2bf(wq[k * 256 + n]);
        wvT[i]  = f2bf(wv[k * 256 + n]);
        fcwT[i] = f2bf(fcw[k * 256 + n]);
    }
    for (int i = t; i < 64 * 64; i += stride) {
        int n = i >> 6, k = i & 63;
        w1T[i] = f2bf(w1[k * 64 + n]);
    }
    // w2 chunk-tiled + swizzled
    for (int i = t; i < 512 * 64; i += stride) {
        int cc  = i >> 12;            // chunk of 64 cols
        int row = (i >> 6) & 63;      // col within chunk
        int kc  = i & 63;
        int n   = cc * 64 + row;      // global output col
        int kl  = kc ^ ((row & 7) << 3);
        w2sw[i] = f2bf(n < 500 ? w2[kl * 500 + n] : 0.f);
    }
    // padded bias (tail -> exp() == 0)
    for (int i = t; i < 512; i += stride)
        b2p[i] = (i < 500) ? b2[i] : -1e30f;
    // zero qh_bf pad rows read by attn (rows >= 128000); b2p lives at 8195072+
    for (int i = t; i < 3072; i += stride)
        qh_bf[8192000 + i] = 0;
    // zero vhT swizzled pad slots: chunk 7, k 52..63 for every (bh, d)
    for (int i = t; i < 196608; i += stride) {
        int bh = i / 768;
        int r  = i - bh * 768;
        int d  = r / 12;
        int kk = 52 + (r - d * 12);
        vhT[((size_t)((bh * 8 + 7) * 64 + d)) * 64 + (kk ^ ((d & 7) << 3))] = 0;
    }
}

// ---------------------------------------------------------------------------
// Kernel 1: head projections, bf16 MFMA.
// grid (500, 2), block 512 = 8 waves in 2x4; block tile 64 rows x 256 cols.
// which=0: qh_bf [bh][500][64]
// which=1: vhT chunk-tiled+swizzled [bh][cc=8][d=64][k=64],
//          vhT[bh][cc][d][k ^ ((d&7)<<3)] = v_head[bh][d][cc*64+k]
// ---------------------------------------------------------------------------
__global__ __launch_bounds__(512) void proj_kernel(
    const float* __restrict__ q, const float* __restrict__ v,
    const u16* __restrict__ wqT, const u16* __restrict__ wvT,
    u16* __restrict__ qh_bf, u16* __restrict__ vhT)
{
    const int which = blockIdx.y;
    const float* __restrict__ x = which ? v : q;
    const u16*   __restrict__ wT = which ? wvT : wqT;

    __shared__ u16 Xs[64][72];    // [m][k], pad 144 B
    __shared__ u16 Ws[256][72];   // [n][k], pad 144 B

    const int tid  = threadIdx.x;
    const int wvid = tid >> 6, ln = tid & 63;
    const int n16  = ln & 15, quad = ln >> 4;
    const int wr   = wvid >> 2, wc = wvid & 3;   // 2 x 4
    const int row0 = blockIdx.x * 64;

    f32x4 acc[2][4];
    #pragma unroll
    for (int mt = 0; mt < 2; mt++)
        #pragma unroll
        for (int nt = 0; nt < 4; nt++) acc[mt][nt] = (f32x4){0.f, 0.f, 0.f, 0.f};

    for (int kc = 0; kc < 256; kc += 64) {
        // stage X (fp32 -> bf16): 64 x 64
        #pragma unroll
        for (int j = 0; j < 2; j++) {
            int idx = tid + 512 * j;
            int m = idx >> 4, k4 = idx & 15;
            float4 a = *(const float4*)&x[(size_t)(row0 + m) * 256 + kc + k4 * 4];
            __align__(8) u16 t4[4] = {f2bf(a.x), f2bf(a.y), f2bf(a.z), f2bf(a.w)};
            *(uint2*)&Xs[m][k4 * 4] = *(const uint2*)t4;
        }
        // stage W^T: 256 x 64 bf16
        #pragma unroll
        for (int j = 0; j < 4; j++) {
            int idx = tid + 512 * j;
            int n = idx >> 3, k8 = idx & 7;
            *(uint4*)&Ws[n][k8 * 8] = *(const uint4*)&wT[n * 256 + kc + k8 * 8];
        }
        __syncthreads();
        #pragma unroll
        for (int ks = 0; ks < 2; ks++) {
            short8 af[2], bfr[4];
            #pragma unroll
            for (int mt = 0; mt < 2; mt++)
                af[mt] = *(const short8*)&Xs[wr * 32 + mt * 16 + n16][ks * 32 + quad * 8];
            #pragma unroll
            for (int nt = 0; nt < 4; nt++)
                bfr[nt] = *(const short8*)&Ws[wc * 64 + nt * 16 + n16][ks * 32 + quad * 8];
            #pragma unroll
            for (int mt = 0; mt < 2; mt++)
                #pragma unroll
                for (int nt = 0; nt < 4; nt++)
                    acc[mt][nt] = __builtin_amdgcn_mfma_f32_16x16x32_bf16(
                        af[mt], bfr[nt], acc[mt][nt], 0, 0, 0);
        }
        __syncthreads();
    }

    // h = wc (64-col groups), d = nt*16 + n16
    if (which == 0) {
        #pragma unroll
        for (int mt = 0; mt < 2; mt++) {
            int m0 = row0 + wr * 32 + mt * 16 + quad * 4;   // mult of 4
            int b  = m0 / 500;
            int l0 = m0 - 500 * b;                           // group never straddles b
            #pragma unroll
            for (int nt = 0; nt < 4; nt++) {
                int d = nt * 16 + n16;
                u16* dst = qh_bf + ((size_t)((b * 4 + wc) * 500 + l0)) * 64 + d;
                #pragma unroll
                for (int i = 0; i < 4; i++)
                    dst[(size_t)i * 64] = f2bf(acc[mt][nt][i]);
            }
        }
    } else {
        #pragma unroll
        for (int mt = 0; mt < 2; mt++) {
            int m0 = row0 + wr * 32 + mt * 16 + quad * 4;
            int b  = m0 / 500;
            int l0 = m0 - 500 * b;                           // 4-aligned
            int cc = l0 >> 6, kk = l0 & 63;
            #pragma unroll
            for (int nt = 0; nt < 4; nt++) {
                int d = nt * 16 + n16;
                __align__(8) u16 t4[4];
                #pragma unroll
                for (int i = 0; i < 4; i++) t4[i] = f2bf(acc[mt][nt][i]);
                size_t base = ((size_t)(((b * 4 + wc) * 8 + cc) * 64 + d)) * 64;
                *(uint2*)&vhT[base + (kk ^ ((d & 7) << 3))] = *(const uint2*)t4;
            }
        }
    }
}

// ---------------------------------------------------------------------------
// Kernel 2: dense-synthesizer attention — chunked, async-LDS-staged (T3).
// grid (256 bh, 4 row-blocks), block 512 = 8 waves, 16 rows/wave (128 rows).
// Per 64-col chunk: stage next chunk's w2 (8KB) + v (8KB) via global_load_lds
// (1 DMA instr per wave per buffer; double-buffered, pre-swizzled global
// layouts -> conflict-free XOR reads), then logits MFMA -> exp -> PV MFMA.
// 8 waves per barrier = 2x compute per staging event vs the 4-wave version;
// half the blocks = half the staging traffic.  LDS 50 KB -> 3 blocks/CU
// (24 waves/CU).  Rows >= 500 are garbage-but-row-independent; masked at
// the epilogue.
// ---------------------------------------------------------------------------
__global__ __launch_bounds__(512, 4) void attn_kernel(
    const u16* __restrict__ qh, const u16* __restrict__ vhT,
    const u16* __restrict__ w1T, const float* __restrict__ b1,
    const u16* __restrict__ w2sw, const float* __restrict__ b2p,
    u16* __restrict__ ctx)
{
    __shared__ __align__(16) u16 w2s[2][4096];    // [buf][row*64 + k^swz]
    __shared__ __align__(16) u16 v_s[2][4096];    // [buf][d*64 + k^swz]
    __shared__ __align__(16) u16 scr[8][16][72];  // per-wave s / P scratch

    const int tid  = threadIdx.x;
    const int wv   = tid >> 6;
    const int ln   = tid & 63;
    const int n16  = ln & 15;
    const int quad = ln >> 4;
    const int bh   = blockIdx.x;
    const int r0   = blockIdx.y * 128 + wv * 16;

    const u16* vg = vhT + (size_t)bh * 32768;     // 8 chunks x 4096

    // issue chunk-0 staging first; latency hides under Phase A
    {
        int off = wv * 512 + ln * 8;
        gload_lds16(w2sw + off, &w2s[0][wv * 512]);
        gload_lds16(vg + off,   &v_s[0][wv * 512]);
    }

    // ---- Phase A: s = relu(qh @ w1 + b1)  (wave-private) ----
    {
        const u16* qbase = qh + ((size_t)(bh * 500 + r0 + n16)) * 64;
        short8 a0 = *(const short8*)(qbase + quad * 8);
        short8 a1 = *(const short8*)(qbase + 32 + quad * 8);
        #pragma unroll
        for (int nt = 0; nt < 4; nt++) {
            const u16* wb = w1T + (nt * 16 + n16) * 64;
            short8 bb0 = *(const short8*)(wb + quad * 8);
            short8 bb1 = *(const short8*)(wb + 32 + quad * 8);
            float bias = b1[nt * 16 + n16];
            f32x4 c = {bias, bias, bias, bias};
            c = __builtin_amdgcn_mfma_f32_16x16x32_bf16(a0, bb0, c, 0, 0, 0);
            c = __builtin_amdgcn_mfma_f32_16x16x32_bf16(a1, bb1, c, 0, 0, 0);
            int col = nt * 16 + n16;
            #pragma unroll
            for (int i = 0; i < 4; i++)
                scr[wv][quad * 4 + i][col] = f2bf(fmaxf(c[i], 0.f));
        }
    }
    short8 sa0 = *(const short8*)&scr[wv][n16][quad * 8];
    short8 sa1 = *(const short8*)&scr[wv][n16][32 + quad * 8];

    f32x4 oacc[4];
    #pragma unroll
    for (int nt = 0; nt < 4; nt++) oacc[nt] = (f32x4){0.f, 0.f, 0.f, 0.f};
    float sm[4] = {0.f, 0.f, 0.f, 0.f};

    __syncthreads();   // chunk-0 staging complete; scr s-values consumed to regs

    #pragma unroll 2
    for (int cc = 0; cc < 8; cc++) {
        const int cur = cc & 1;
        if (cc < 7) {   // stage next chunk into the other buffer
            int off = (cc + 1) * 4096 + wv * 512 + ln * 8;
            gload_lds16(w2sw + off, &w2s[cur ^ 1][wv * 512]);
            gload_lds16(vg + off,   &v_s[cur ^ 1][wv * 512]);
        }
        const u16* wb   = &w2s[cur][0];
        const u16* vbuf = &v_s[cur][0];

        // logits: 4 col-tiles of 16
        f32x4 c8[4];
        #pragma unroll
        for (int t = 0; t < 4; t++) {
            int r  = t * 16 + n16;
            int sw = (r & 7) << 3;
            short8 b0  = *(const short8*)&wb[r * 64 + ((quad * 8) ^ sw)];
            short8 b1v = *(const short8*)&wb[r * 64 + ((32 + quad * 8) ^ sw)];
            float bias = b2p[cc * 64 + r];
            f32x4 c = {bias, bias, bias, bias};
            c = __builtin_amdgcn_mfma_f32_16x16x32_bf16(sa0, b0, c, 0, 0, 0);
            c = __builtin_amdgcn_mfma_f32_16x16x32_bf16(sa1, b1v, c, 0, 0, 0);
            c8[t] = c;
        }
        // exp (no max-pass) + running sum; P -> bf16 -> wave-local scratch
        #pragma unroll
        for (int t = 0; t < 4; t++) {
            int col = t * 16 + n16;
            #pragma unroll
            for (int i = 0; i < 4; i++) {
                float e = __expf(c8[t][i]);
                sm[i] += e;
                scr[wv][quad * 4 + i][col] = f2bf(e);
            }
        }
        // PV on this chunk
        #pragma unroll
        for (int ks = 0; ks < 2; ks++) {
            short8 pa = *(const short8*)&scr[wv][n16][ks * 32 + quad * 8];
            #pragma unroll
            for (int nt = 0; nt < 4; nt++) {
                int d   = nt * 16 + n16;
                int swd = (d & 7) << 3;
                short8 vb2 = *(const short8*)&vbuf[d * 64 + ((ks * 32 + quad * 8) ^ swd)];
                oacc[nt] = __builtin_amdgcn_mfma_f32_16x16x32_bf16(pa, vb2, oacc[nt], 0, 0, 0);
            }
        }
        __syncthreads();   // drains staging vmcnt + protects buffer reuse
    }

    // ---- row-sum reduce over the 16 col-lanes, then scaled bf16 store ----
    #pragma unroll
    for (int off = 1; off < 16; off <<= 1) {
        #pragma unroll
        for (int i = 0; i < 4; i++) sm[i] += __shfl_xor(sm[i], off);
    }

    const int b = bh >> 2, h = bh & 3;
    #pragma unroll
    for (int i = 0; i < 4; i++) {
        int lrow = r0 + quad * 4 + i;
        if (lrow < 500) {
            float s = 1.f / sm[i];
            u16* dst = &ctx[((size_t)(b * 500 + lrow)) * 256 + h * 64];
            #pragma unroll
            for (int nt = 0; nt < 4; nt++)
                dst[nt * 16 + n16] = f2bf(oacc[nt][i] * s);
        }
    }
}

// ---------------------------------------------------------------------------
// Kernel 3: out = LayerNorm(ctx @ fc_w + q), bf16 MFMA + fused LN epilogue.
// grid (500), block 512 = 8 waves in 2x4; block tile 64 rows x 256 cols.
// ---------------------------------------------------------------------------
__global__ __launch_bounds__(512) void final_kernel(
    const u16* __restrict__ ctx, const u16* __restrict__ fcwT,
    const float* __restrict__ qres, const float* __restrict__ g,
    const float* __restrict__ bta, float* __restrict__ out)
{
    __shared__ u16 Xs[64][72];
    __shared__ u16 Ws[256][72];
    __shared__ float red[4][2][64];   // [wc][s1|s2][row]
    __shared__ float murs[2][64];     // [mu|rs][row]

    const int tid  = threadIdx.x;
    const int wvid = tid >> 6, ln = tid & 63;
    const int n16  = ln & 15, quad = ln >> 4;
    const int wr   = wvid >> 2, wc = wvid & 3;   // 2 x 4
    const int row0 = blockIdx.x * 64;

    f32x4 acc[2][4];
    #pragma unroll
    for (int mt = 0; mt < 2; mt++)
        #pragma unroll
        for (int nt = 0; nt < 4; nt++) acc[mt][nt] = (f32x4){0.f, 0.f, 0.f, 0.f};

    for (int kc = 0; kc < 256; kc += 64) {
        // stage X: 64 x 64 bf16
        {
            int idx = tid;
            int m = idx >> 3, k8 = idx & 7;
            *(uint4*)&Xs[m][k8 * 8] =
                *(const uint4*)&ctx[(size_t)(row0 + m) * 256 + kc + k8 * 8];
        }
        // stage W^T: 256 x 64 bf16
        #pragma unroll
        for (int j = 0; j < 4; j++) {
            int idx = tid + 512 * j;
            int n = idx >> 3, k8 = idx & 7;
            *(uint4*)&Ws[n][k8 * 8] = *(const uint4*)&fcwT[n * 256 + kc + k8 * 8];
        }
        __syncthreads();
        #pragma unroll
        for (int ks = 0; ks < 2; ks++) {
            short8 af[2], bfr[4];
            #pragma unroll
            for (int mt = 0; mt < 2; mt++)
                af[mt] = *(const short8*)&Xs[wr * 32 + mt * 16 + n16][ks * 32 + quad * 8];
            #pragma unroll
            for (int nt = 0; nt < 4; nt++)
                bfr[nt] = *(const short8*)&Ws[wc * 64 + nt * 16 + n16][ks * 32 + quad * 8];
            #pragma unroll
            for (int mt = 0; mt < 2; mt++)
                #pragma unroll
                for (int nt = 0; nt < 4; nt++)
                    acc[mt][nt] = __builtin_amdgcn_mfma_f32_16x16x32_bf16(
                        af[mt], bfr[nt], acc[mt][nt], 0, 0, 0);
        }
        __syncthreads();
    }

    // residual add
    #pragma unroll
    for (int mt = 0; mt < 2; mt++) {
        int m0 = row0 + wr * 32 + mt * 16 + quad * 4;
        #pragma unroll
        for (int i = 0; i < 4; i++) {
            const float* rp = &qres[(size_t)(m0 + i) * 256 + wc * 64 + n16];
            #pragma unroll
            for (int nt = 0; nt < 4; nt++)
                acc[mt][nt][i] += rp[nt * 16];
        }
    }
    // per-row partial sums -> LDS
    #pragma unroll
    for (int mt = 0; mt < 2; mt++) {
        #pragma unroll
        for (int i = 0; i < 4; i++) {
            float s1 = 0.f, s2 = 0.f;
            #pragma unroll
            for (int nt = 0; nt < 4; nt++) {
                float vv = acc[mt][nt][i];
                s1 += vv; s2 += vv * vv;
            }
            #pragma unroll
            for (int off = 1; off < 16; off <<= 1) {
                s1 += __shfl_xor(s1, off);
                s2 += __shfl_xor(s2, off);
            }
            if (n16 == 0) {
                int r = wr * 32 + mt * 16 + quad * 4 + i;
                red[wc][0][r] = s1;
                red[wc][1][r] = s2;
            }
        }
    }
    __syncthreads();
    if (tid < 64) {
        float S1 = red[0][0][tid] + red[1][0][tid] + red[2][0][tid] + red[3][0][tid];
        float S2 = red[0][1][tid] + red[1][1][tid] + red[2][1][tid] + red[3][1][tid];
        float mu  = S1 * 0.00390625f;
        float var = S2 * 0.00390625f - mu * mu;
        murs[0][tid] = mu;
        murs[1][tid] = rsqrtf(var + 1e-6f);
    }
    __syncthreads();

    float gv[4], bv[4];
    #pragma unroll
    for (int nt = 0; nt < 4; nt++) {
        int col = wc * 64 + nt * 16 + n16;
        gv[nt] = g[col];
        bv[nt] = bta[col];
    }
    #pragma unroll
    for (int mt = 0; mt < 2; mt++) {
        int rb = wr * 32 + mt * 16 + quad * 4;
        #pragma unroll
        for (int i = 0; i < 4; i++) {
            float mu = murs[0][rb + i];
            float rs = murs[1][rb + i];
            float* op = &out[(size_t)(row0 + rb + i) * 256 + wc * 64 + n16];
            #pragma unroll
            for (int nt = 0; nt < 4; nt++)
                op[nt * 16] = (acc[mt][nt][i] - mu) * rs * gv[nt] + bv[nt];
        }
    }
}

// ---------------------------------------------------------------------------
extern "C" void kernel_launch(void* const* d_in, const int* in_sizes, int n_in,
                              void* d_out, int out_size, void* d_ws, size_t ws_size,
                              hipStream_t stream)
{
    const float* q   = (const float*)d_in[0];
    const float* v   = (const float*)d_in[2];
    const float* wqs = (const float*)d_in[3];
    const float* wvs = (const float*)d_in[4];
    const float* w1  = (const float*)d_in[5];
    const float* b1  = (const float*)d_in[6];
    const float* w2  = (const float*)d_in[7];
    const float* b2  = (const float*)d_in[8];
    const float* fcw = (const float*)d_in[9];
    const float* lng = (const float*)d_in[10];
    const float* lnb = (const float*)d_in[11];
    float* out = (float*)d_out;

    u16* qh_bf = (u16*)d_ws;            // 8,200,192 (rows >=500*256 are pad)
    u16* vhT   = qh_bf + 8200192;       // 8,388,608 (chunk-tiled + swizzled)
    u16* w1T   = vhT + 8388608;         // 4,096
    u16* w2sw  = w1T + 4096;            // 32,768 (chunk-tiled + swizzled)
    u16* wqT   = w2sw + 32768;          // 65,536
    u16* wvT   = wqT + 65536;           // 65,536
    u16* fcwT  = wvT + 65536;           // 65,536
    u16* ctx   = fcwT + 65536;          // 8,192,000
    float* b2p = (float*)(qh_bf + 8195072);  // 512 floats inside qh_bf tail pad

    prep_kernel <<<dim3(64),     256, 0, stream>>>(wqs, wvs, fcw, w1, w2, b2,
                                                   wqT, wvT, fcwT, w1T, w2sw,
                                                   qh_bf, vhT, b2p);
    proj_kernel <<<dim3(500, 2), 512, 0, stream>>>(q, v, wqT, wvT, qh_bf, vhT);
    attn_kernel <<<dim3(256, 4), 512, 0, stream>>>(qh_bf, vhT, w1T, b1, w2sw, b2p, ctx);
    final_kernel<<<dim3(500),    512, 0, stream>>>(ctx, fcwT, q, lng, lnb, out);
}

// Round 5
// 91.334 us; speedup vs baseline: 1.9898x; 1.0464x over previous
//
#include <hip/hip_runtime.h>
#include <math.h>

#define B_   64
#define L_   500
#define F_   256
#define H_   4
#define DK   64

typedef unsigned short u16;
typedef unsigned int   u32;
typedef __attribute__((ext_vector_type(8))) short short8;
typedef __attribute__((ext_vector_type(4))) float f32x4;

static __device__ __forceinline__ u16 f2bf(float f) {
    u32 u = __float_as_uint(f);
    u32 r = (u + 0x7FFFu + ((u >> 16) & 1u)) >> 16;
    return (u16)r;
}
// round-half-up bf16 (2 ops); differs from RNE only on exact ties
static __device__ __forceinline__ u16 f2bf_up(float f) {
    return (u16)((__float_as_uint(f) + 0x8000u) >> 16);
}

typedef __attribute__((address_space(3))) u32 lds32;
typedef const __attribute__((address_space(1))) u32 gbl32;
// async global->LDS DMA, 16 B/lane, LDS dest = uniform base + lane*16
static __device__ __forceinline__ void gload_lds16(const u16* g, u16* l) {
    __builtin_amdgcn_global_load_lds((gbl32*)g, (lds32*)l, 16, 0, 0);
}

// ---------------------------------------------------------------------------
// Prep: bf16 transposed weights + padded b2 + pad-zeroing of ws regions.
//  wqT/wvT/fcwT [256][256] ([n][k]); w1T[64][64]
//  w2sw: chunk-tiled + XOR-swizzled: [cc=8][row=64][k=64],
//        w2sw[cc][row][k] = w2[k ^ ((row&7)<<3)][cc*64+row]  (col>=500 -> 0)
//  b2p[512] float (tail -1e30); zero qh_bf pad rows + vhT swizzled pad slots.
// ---------------------------------------------------------------------------
__global__ __launch_bounds__(256) void prep_kernel(
    const float* __restrict__ wq, const float* __restrict__ wv,
    const float* __restrict__ fcw, const float* __restrict__ w1,
    const float* __restrict__ w2, const float* __restrict__ b2,
    u16* __restrict__ wqT, u16* __restrict__ wvT, u16* __restrict__ fcwT,
    u16* __restrict__ w1T, u16* __restrict__ w2sw,
    u16* __restrict__ qh_bf, u16* __restrict__ vhT, float* __restrict__ b2p)
{
    int t = blockIdx.x * 256 + threadIdx.x;
    int stride = gridDim.x * 256;                 // 16384
    for (int i = t; i < 256 * 256; i += stride) {
        int n = i >> 8, k = i & 255;
        wqT[i]  = f2bf(wq[k * 256 + n]);
        wvT[i]  = f2bf(wv[k * 256 + n]);
        fcwT[i] = f2bf(fcw[k * 256 + n]);
    }
    for (int i = t; i < 64 * 64; i += stride) {
        int n = i >> 6, k = i & 63;
        w1T[i] = f2bf(w1[k * 64 + n]);
    }
    // w2 chunk-tiled + swizzled
    for (int i = t; i < 512 * 64; i += stride) {
        int cc  = i >> 12;            // chunk of 64 cols
        int row = (i >> 6) & 63;      // col within chunk
        int kc  = i & 63;
        int n   = cc * 64 + row;      // global output col
        int kl  = kc ^ ((row & 7) << 3);
        w2sw[i] = f2bf(n < 500 ? w2[kl * 500 + n] : 0.f);
    }
    // padded bias (tail -> exp() == 0)
    for (int i = t; i < 512; i += stride)
        b2p[i] = (i < 500) ? b2[i] : -1e30f;
    // zero qh_bf pad rows read by attn (rows >= 128000); b2p lives at 8195072+
    for (int i = t; i < 3072; i += stride)
        qh_bf[8192000 + i] = 0;
    // zero vhT swizzled pad slots: chunk 7, k 52..63 for every (bh, d)
    for (int i = t; i < 196608; i += stride) {
        int bh = i / 768;
        int r  = i - bh * 768;
        int d  = r / 12;
        int kk = 52 + (r - d * 12);
        vhT[((size_t)((bh * 8 + 7) * 64 + d)) * 64 + (kk ^ ((d & 7) << 3))] = 0;
    }
}

// ---------------------------------------------------------------------------
// Kernel 1: head projections, bf16 MFMA.
// grid (500, 2), block 512 = 8 waves in 2x4; block tile 64 rows x 256 cols.
// which=0: qh_bf [bh][500][64]
// which=1: vhT chunk-tiled+swizzled [bh][cc=8][d=64][k=64],
//          vhT[bh][cc][d][k ^ ((d&7)<<3)] = v_head[bh][d][cc*64+k]
// ---------------------------------------------------------------------------
__global__ __launch_bounds__(512) void proj_kernel(
    const float* __restrict__ q, const float* __restrict__ v,
    const u16* __restrict__ wqT, const u16* __restrict__ wvT,
    u16* __restrict__ qh_bf, u16* __restrict__ vhT)
{
    const int which = blockIdx.y;
    const float* __restrict__ x = which ? v : q;
    const u16*   __restrict__ wT = which ? wvT : wqT;

    __shared__ u16 Xs[64][72];    // [m][k], pad 144 B
    __shared__ u16 Ws[256][72];   // [n][k], pad 144 B

    const int tid  = threadIdx.x;
    const int wvid = tid >> 6, ln = tid & 63;
    const int n16  = ln & 15, quad = ln >> 4;
    const int wr   = wvid >> 2, wc = wvid & 3;   // 2 x 4
    const int row0 = blockIdx.x * 64;

    f32x4 acc[2][4];
    #pragma unroll
    for (int mt = 0; mt < 2; mt++)
        #pragma unroll
        for (int nt = 0; nt < 4; nt++) acc[mt][nt] = (f32x4){0.f, 0.f, 0.f, 0.f};

    for (int kc = 0; kc < 256; kc += 64) {
        // stage X (fp32 -> bf16): 64 x 64
        #pragma unroll
        for (int j = 0; j < 2; j++) {
            int idx = tid + 512 * j;
            int m = idx >> 4, k4 = idx & 15;
            float4 a = *(const float4*)&x[(size_t)(row0 + m) * 256 + kc + k4 * 4];
            __align__(8) u16 t4[4] = {f2bf(a.x), f2bf(a.y), f2bf(a.z), f2bf(a.w)};
            *(uint2*)&Xs[m][k4 * 4] = *(const uint2*)t4;
        }
        // stage W^T: 256 x 64 bf16
        #pragma unroll
        for (int j = 0; j < 4; j++) {
            int idx = tid + 512 * j;
            int n = idx >> 3, k8 = idx & 7;
            *(uint4*)&Ws[n][k8 * 8] = *(const uint4*)&wT[n * 256 + kc + k8 * 8];
        }
        __syncthreads();
        #pragma unroll
        for (int ks = 0; ks < 2; ks++) {
            short8 af[2], bfr[4];
            #pragma unroll
            for (int mt = 0; mt < 2; mt++)
                af[mt] = *(const short8*)&Xs[wr * 32 + mt * 16 + n16][ks * 32 + quad * 8];
            #pragma unroll
            for (int nt = 0; nt < 4; nt++)
                bfr[nt] = *(const short8*)&Ws[wc * 64 + nt * 16 + n16][ks * 32 + quad * 8];
            #pragma unroll
            for (int mt = 0; mt < 2; mt++)
                #pragma unroll
                for (int nt = 0; nt < 4; nt++)
                    acc[mt][nt] = __builtin_amdgcn_mfma_f32_16x16x32_bf16(
                        af[mt], bfr[nt], acc[mt][nt], 0, 0, 0);
        }
        __syncthreads();
    }

    // h = wc (64-col groups), d = nt*16 + n16
    if (which == 0) {
        #pragma unroll
        for (int mt = 0; mt < 2; mt++) {
            int m0 = row0 + wr * 32 + mt * 16 + quad * 4;   // mult of 4
            int b  = m0 / 500;
            int l0 = m0 - 500 * b;                           // group never straddles b
            #pragma unroll
            for (int nt = 0; nt < 4; nt++) {
                int d = nt * 16 + n16;
                u16* dst = qh_bf + ((size_t)((b * 4 + wc) * 500 + l0)) * 64 + d;
                #pragma unroll
                for (int i = 0; i < 4; i++)
                    dst[(size_t)i * 64] = f2bf(acc[mt][nt][i]);
            }
        }
    } else {
        #pragma unroll
        for (int mt = 0; mt < 2; mt++) {
            int m0 = row0 + wr * 32 + mt * 16 + quad * 4;
            int b  = m0 / 500;
            int l0 = m0 - 500 * b;                           // 4-aligned
            int cc = l0 >> 6, kk = l0 & 63;
            #pragma unroll
            for (int nt = 0; nt < 4; nt++) {
                int d = nt * 16 + n16;
                __align__(8) u16 t4[4];
                #pragma unroll
                for (int i = 0; i < 4; i++) t4[i] = f2bf(acc[mt][nt][i]);
                size_t base = ((size_t)(((b * 4 + wc) * 8 + cc) * 64 + d)) * 64;
                *(uint2*)&vhT[base + (kk ^ ((d & 7) << 3))] = *(const uint2*)t4;
            }
        }
    }
}

// ---------------------------------------------------------------------------
// Kernel 2: dense-synthesizer attention — whole-bh-in-LDS, barrier-once.
// grid (256) = 1 block/bh = 1 block/CU, exactly one scheduling round.
// Block 512 = 8 waves x 4 row-groups x 16 rows = all 512 (500) rows of bh.
// Stage ALL of w2 (64KB) + vhT[bh] (64KB) + b2 (2KB) once via global_load_lds
// (issued after the Phase-A input loads, pinned with sched_barrier so Phase A
// doesn't drain the DMA queue), ONE __syncthreads, then 4 rg x 8 chunks of
// pure-LDS MFMA/exp with zero synchronization (w2/v read-only, scratch
// wave-private).  LDS 148.5 KB -> 1 block/CU by design.
// ---------------------------------------------------------------------------
__global__ __launch_bounds__(512, 2) void attn_kernel(
    const u16* __restrict__ qh, const u16* __restrict__ vhT,
    const u16* __restrict__ w1T, const float* __restrict__ b1,
    const u16* __restrict__ w2sw, const float* __restrict__ b2p,
    u16* __restrict__ ctx)
{
    __shared__ __align__(16) u16 w2all[32768];    // [cc][row][k^swz]
    __shared__ __align__(16) u16 vall[32768];     // [cc][d][k^swz]
    __shared__ __align__(16) float b2s[512];
    __shared__ __align__(16) u16 scr[8][16][72];  // per-wave s / P scratch

    const int tid  = threadIdx.x;
    const int wv   = tid >> 6;
    const int ln   = tid & 63;
    const int n16  = ln & 15;
    const int quad = ln >> 4;
    const int bh   = blockIdx.x;

    const u16* vg = vhT + (size_t)bh * 32768;

    // ---- (a) Phase-A input loads FIRST (oldest in vmcnt queue) ----
    short8 a0[4], a1[4];
    #pragma unroll
    for (int rg = 0; rg < 4; rg++) {
        const u16* qbase = qh + ((size_t)(bh * 500 + rg * 128 + wv * 16 + n16)) * 64;
        a0[rg] = *(const short8*)(qbase + quad * 8);
        a1[rg] = *(const short8*)(qbase + 32 + quad * 8);
    }
    short8 w1b0[4], w1b1[4];
    float  b1v[4];
    #pragma unroll
    for (int nt = 0; nt < 4; nt++) {
        const u16* wb = w1T + (nt * 16 + n16) * 64;
        w1b0[nt] = *(const short8*)(wb + quad * 8);
        w1b1[nt] = *(const short8*)(wb + 32 + quad * 8);
        b1v[nt]  = b1[nt * 16 + n16];
    }
    __builtin_amdgcn_sched_barrier(0);

    // ---- (b) one-shot staging: 16 KB per wave (16 DMA) + b2 ----
    {
        int base = wv * 4096;
        #pragma unroll
        for (int j = 0; j < 8; j++)
            gload_lds16(w2sw + base + j * 512 + ln * 8, &w2all[base + j * 512]);
        #pragma unroll
        for (int j = 0; j < 8; j++)
            gload_lds16(vg + base + j * 512 + ln * 8, &vall[base + j * 512]);
        if (wv < 2)
            gload_lds16((const u16*)b2p + wv * 512 + ln * 8, (u16*)&b2s[wv * 256]);
    }
    __builtin_amdgcn_sched_barrier(0);

    // ---- (c) Phase A for all 4 row-groups (hides DMA latency) ----
    short8 sa0[4], sa1[4];
    #pragma unroll
    for (int rg = 0; rg < 4; rg++) {
        #pragma unroll
        for (int nt = 0; nt < 4; nt++) {
            float bias = b1v[nt];
            f32x4 c = {bias, bias, bias, bias};
            c = __builtin_amdgcn_mfma_f32_16x16x32_bf16(a0[rg], w1b0[nt], c, 0, 0, 0);
            c = __builtin_amdgcn_mfma_f32_16x16x32_bf16(a1[rg], w1b1[nt], c, 0, 0, 0);
            int col = nt * 16 + n16;
            #pragma unroll
            for (int i = 0; i < 4; i++)
                scr[wv][quad * 4 + i][col] = f2bf(fmaxf(c[i], 0.f));
        }
        sa0[rg] = *(const short8*)&scr[wv][n16][quad * 8];
        sa1[rg] = *(const short8*)&scr[wv][n16][32 + quad * 8];
    }

    __syncthreads();   // the ONLY barrier: staging complete, scr free

    // ---- (d) main: 4 row-groups x 8 chunks, pure LDS, no sync ----
    const int b = bh >> 2, h = bh & 3;
    #pragma unroll
    for (int rg = 0; rg < 4; rg++) {
        f32x4 oacc[4];
        #pragma unroll
        for (int nt = 0; nt < 4; nt++) oacc[nt] = (f32x4){0.f, 0.f, 0.f, 0.f};
        float sm[4] = {0.f, 0.f, 0.f, 0.f};

        #pragma unroll 2
        for (int cc = 0; cc < 8; cc++) {
            // logits: 4 col-tiles of 16
            f32x4 c8[4];
            #pragma unroll
            for (int t = 0; t < 4; t++) {
                int r  = t * 16 + n16;
                int sw = (r & 7) << 3;
                const u16* wb = &w2all[cc * 4096 + r * 64];
                short8 b0  = *(const short8*)&wb[(quad * 8) ^ sw];
                short8 b1f = *(const short8*)&wb[(32 + quad * 8) ^ sw];
                float bias = b2s[cc * 64 + r];
                f32x4 c = {bias, bias, bias, bias};
                c = __builtin_amdgcn_mfma_f32_16x16x32_bf16(sa0[rg], b0, c, 0, 0, 0);
                c = __builtin_amdgcn_mfma_f32_16x16x32_bf16(sa1[rg], b1f, c, 0, 0, 0);
                c8[t] = c;
            }
            // exp (no max-pass) + running sum; P -> bf16 (half-up) -> scratch
            #pragma unroll
            for (int t = 0; t < 4; t++) {
                int col = t * 16 + n16;
                #pragma unroll
                for (int i = 0; i < 4; i++) {
                    float e = __expf(c8[t][i]);
                    sm[i] += e;
                    scr[wv][quad * 4 + i][col] = f2bf_up(e);
                }
            }
            // PV on this chunk
            #pragma unroll
            for (int ks = 0; ks < 2; ks++) {
                short8 pa = *(const short8*)&scr[wv][n16][ks * 32 + quad * 8];
                #pragma unroll
                for (int nt = 0; nt < 4; nt++) {
                    int d   = nt * 16 + n16;
                    int swd = (d & 7) << 3;
                    short8 vb2 = *(const short8*)&vall[cc * 4096 + d * 64 +
                                                       ((ks * 32 + quad * 8) ^ swd)];
                    oacc[nt] = __builtin_amdgcn_mfma_f32_16x16x32_bf16(
                        pa, vb2, oacc[nt], 0, 0, 0);
                }
            }
        }

        // row-sum reduce over the 16 col-lanes, then scaled bf16 store
        #pragma unroll
        for (int off = 1; off < 16; off <<= 1) {
            #pragma unroll
            for (int i = 0; i < 4; i++) sm[i] += __shfl_xor(sm[i], off);
        }
        #pragma unroll
        for (int i = 0; i < 4; i++) {
            int lrow = rg * 128 + wv * 16 + quad * 4 + i;
            if (lrow < 500) {
                float s = 1.f / sm[i];
                u16* dst = &ctx[((size_t)(b * 500 + lrow)) * 256 + h * 64];
                #pragma unroll
                for (int nt = 0; nt < 4; nt++)
                    dst[nt * 16 + n16] = f2bf(oacc[nt][i] * s);
            }
        }
    }
}

// ---------------------------------------------------------------------------
// Kernel 3: out = LayerNorm(ctx @ fc_w + q), bf16 MFMA + fused LN epilogue.
// grid (500), block 512 = 8 waves in 2x4; block tile 64 rows x 256 cols.
// ---------------------------------------------------------------------------
__global__ __launch_bounds__(512) void final_kernel(
    const u16* __restrict__ ctx, const u16* __restrict__ fcwT,
    const float* __restrict__ qres, const float* __restrict__ g,
    const float* __restrict__ bta, float* __restrict__ out)
{
    __shared__ u16 Xs[64][72];
    __shared__ u16 Ws[256][72];
    __shared__ float red[4][2][64];   // [wc][s1|s2][row]
    __shared__ float murs[2][64];     // [mu|rs][row]

    const int tid  = threadIdx.x;
    const int wvid = tid >> 6, ln = tid & 63;
    const int n16  = ln & 15, quad = ln >> 4;
    const int wr   = wvid >> 2, wc = wvid & 3;   // 2 x 4
    const int row0 = blockIdx.x * 64;

    f32x4 acc[2][4];
    #pragma unroll
    for (int mt = 0; mt < 2; mt++)
        #pragma unroll
        for (int nt = 0; nt < 4; nt++) acc[mt][nt] = (f32x4){0.f, 0.f, 0.f, 0.f};

    for (int kc = 0; kc < 256; kc += 64) {
        // stage X: 64 x 64 bf16
        {
            int idx = tid;
            int m = idx >> 3, k8 = idx & 7;
            *(uint4*)&Xs[m][k8 * 8] =
                *(const uint4*)&ctx[(size_t)(row0 + m) * 256 + kc + k8 * 8];
        }
        // stage W^T: 256 x 64 bf16
        #pragma unroll
        for (int j = 0; j < 4; j++) {
            int idx = tid + 512 * j;
            int n = idx >> 3, k8 = idx & 7;
            *(uint4*)&Ws[n][k8 * 8] = *(const uint4*)&fcwT[n * 256 + kc + k8 * 8];
        }
        __syncthreads();
        #pragma unroll
        for (int ks = 0; ks < 2; ks++) {
            short8 af[2], bfr[4];
            #pragma unroll
            for (int mt = 0; mt < 2; mt++)
                af[mt] = *(const short8*)&Xs[wr * 32 + mt * 16 + n16][ks * 32 + quad * 8];
            #pragma unroll
            for (int nt = 0; nt < 4; nt++)
                bfr[nt] = *(const short8*)&Ws[wc * 64 + nt * 16 + n16][ks * 32 + quad * 8];
            #pragma unroll
            for (int mt = 0; mt < 2; mt++)
                #pragma unroll
                for (int nt = 0; nt < 4; nt++)
                    acc[mt][nt] = __builtin_amdgcn_mfma_f32_16x16x32_bf16(
                        af[mt], bfr[nt], acc[mt][nt], 0, 0, 0);
        }
        __syncthreads();
    }

    // residual add
    #pragma unroll
    for (int mt = 0; mt < 2; mt++) {
        int m0 = row0 + wr * 32 + mt * 16 + quad * 4;
        #pragma unroll
        for (int i = 0; i < 4; i++) {
            const float* rp = &qres[(size_t)(m0 + i) * 256 + wc * 64 + n16];
            #pragma unroll
            for (int nt = 0; nt < 4; nt++)
                acc[mt][nt][i] += rp[nt * 16];
        }
    }
    // per-row partial sums -> LDS
    #pragma unroll
    for (int mt = 0; mt < 2; mt++) {
        #pragma unroll
        for (int i = 0; i < 4; i++) {
            float s1 = 0.f, s2 = 0.f;
            #pragma unroll
            for (int nt = 0; nt < 4; nt++) {
                float vv = acc[mt][nt][i];
                s1 += vv; s2 += vv * vv;
            }
            #pragma unroll
            for (int off = 1; off < 16; off <<= 1) {
                s1 += __shfl_xor(s1, off);
                s2 += __shfl_xor(s2, off);
            }
            if (n16 == 0) {
                int r = wr * 32 + mt * 16 + quad * 4 + i;
                red[wc][0][r] = s1;
                red[wc][1][r] = s2;
            }
        }
    }
    __syncthreads();
    if (tid < 64) {
        float S1 = red[0][0][tid] + red[1][0][tid] + red[2][0][tid] + red[3][0][tid];
        float S2 = red[0][1][tid] + red[1][1][tid] + red[2][1][tid] + red[3][1][tid];
        float mu  = S1 * 0.00390625f;
        float var = S2 * 0.00390625f - mu * mu;
        murs[0][tid] = mu;
        murs[1][tid] = rsqrtf(var + 1e-6f);
    }
    __syncthreads();

    float gv[4], bv[4];
    #pragma unroll
    for (int nt = 0; nt < 4; nt++) {
        int col = wc * 64 + nt * 16 + n16;
        gv[nt] = g[col];
        bv[nt] = bta[col];
    }
    #pragma unroll
    for (int mt = 0; mt < 2; mt++) {
        int rb = wr * 32 + mt * 16 + quad * 4;
        #pragma unroll
        for (int i = 0; i < 4; i++) {
            float mu = murs[0][rb + i];
            float rs = murs[1][rb + i];
            float* op = &out[(size_t)(row0 + rb + i) * 256 + wc * 64 + n16];
            #pragma unroll
            for (int nt = 0; nt < 4; nt++)
                op[nt * 16] = (acc[mt][nt][i] - mu) * rs * gv[nt] + bv[nt];
        }
    }
}

// ---------------------------------------------------------------------------
extern "C" void kernel_launch(void* const* d_in, const int* in_sizes, int n_in,
                              void* d_out, int out_size, void* d_ws, size_t ws_size,
                              hipStream_t stream)
{
    const float* q   = (const float*)d_in[0];
    const float* v   = (const float*)d_in[2];
    const float* wqs = (const float*)d_in[3];
    const float* wvs = (const float*)d_in[4];
    const float* w1  = (const float*)d_in[5];
    const float* b1  = (const float*)d_in[6];
    const float* w2  = (const float*)d_in[7];
    const float* b2  = (const float*)d_in[8];
    const float* fcw = (const float*)d_in[9];
    const float* lng = (const float*)d_in[10];
    const float* lnb = (const float*)d_in[11];
    float* out = (float*)d_out;

    u16* qh_bf = (u16*)d_ws;            // 8,200,192 (rows >=500*256 are pad)
    u16* vhT   = qh_bf + 8200192;       // 8,388,608 (chunk-tiled + swizzled)
    u16* w1T   = vhT + 8388608;         // 4,096
    u16* w2sw  = w1T + 4096;            // 32,768 (chunk-tiled + swizzled)
    u16* wqT   = w2sw + 32768;          // 65,536
    u16* wvT   = wqT + 65536;           // 65,536
    u16* fcwT  = wvT + 65536;           // 65,536
    u16* ctx   = fcwT + 65536;          // 8,192,000
    float* b2p = (float*)(qh_bf + 8195072);  // 512 floats inside qh_bf tail pad

    prep_kernel <<<dim3(64),     256, 0, stream>>>(wqs, wvs, fcw, w1, w2, b2,
                                                   wqT, wvT, fcwT, w1T, w2sw,
                                                   qh_bf, vhT, b2p);
    proj_kernel <<<dim3(500, 2), 512, 0, stream>>>(q, v, wqT, wvT, qh_bf, vhT);
    attn_kernel <<<dim3(256),    512, 0, stream>>>(qh_bf, vhT, w1T, b1, w2sw, b2p, ctx);
    final_kernel<<<dim3(500),    512, 0, stream>>>(ctx, fcwT, q, lng, lnb, out);
}